// Round 3
// baseline (1084.770 us; speedup 1.0000x reference)
//
#include <hip/hip_runtime.h>
#include <math.h>

#define NN 100000      // nodes
#define NE 3200000     // edges
#define INF 512        // in feat
#define HID 32         // hidden
#define NC 7           // classes
#define NBUK 391       // ceil(NN/256) node buckets of 256

// ---------------- dtype detection: int64 (flag=1) vs int32 (flag=0) ----------------
__global__ void k_detect(const unsigned* __restrict__ edges, int* __restrict__ flag){
    __shared__ int nz;
    if (threadIdx.x == 0) nz = 0;
    __syncthreads();
    if (edges[2*threadIdx.x + 1] != 0u) atomicOr(&nz, 1);
    __syncthreads();
    if (threadIdx.x == 0) *flag = (nz == 0) ? 1 : 0;
}

// ---------------- bucket histogram (LDS-aggregated) ----------------
__global__ __launch_bounds__(256) void k_bhist(const void* __restrict__ edges, const int* __restrict__ flag,
                                               int* __restrict__ bhist){
    __shared__ int h[NBUK];
    for (int i = threadIdx.x; i < NBUK; i += 256) h[i] = 0;
    __syncthreads();
    const bool f = (*flag != 0);
    const int stride = gridDim.x * 256;
    for (int e = blockIdx.x*256 + threadIdx.x; e < NE; e += stride){
        int d = f ? (int)((const long long*)edges)[NE + e] : ((const int*)edges)[NE + e];
        atomicAdd(&h[d >> 8], 1);
    }
    __syncthreads();
    for (int i = threadIdx.x; i < NBUK; i += 256) if (h[i]) atomicAdd(&bhist[i], h[i]);
}

// ---------------- scan buckets (single block) ----------------
__global__ __launch_bounds__(512) void k_bscan(const int* __restrict__ bhist, int* __restrict__ bptr,
                                               int* __restrict__ bcur){
    __shared__ int sd[512];
    int t = threadIdx.x;
    int v = (t < NBUK) ? bhist[t] : 0;
    sd[t] = v;
    __syncthreads();
    for (int off = 1; off < 512; off <<= 1){
        int a = (t >= off) ? sd[t - off] : 0;
        __syncthreads();
        sd[t] += a;
        __syncthreads();
    }
    if (t < NBUK){ bptr[t] = sd[t] - v; bcur[t] = sd[t] - v; }
    if (t == 0) bptr[NBUK] = NE;
}

// ---------------- block-aggregated bucket scatter ----------------
#define C_T 512
#define C_E 16
__global__ __launch_bounds__(C_T) void k_scatter(const void* __restrict__ edges, const int* __restrict__ flag,
                                                 int* __restrict__ bcur, int* __restrict__ ebuf){
    __shared__ int hist[NBUK];
    __shared__ int gbase[NBUK];
    for (int i = threadIdx.x; i < NBUK; i += C_T) hist[i] = 0;
    __syncthreads();
    const bool f = (*flag != 0);
    const int base = blockIdx.x * (C_T * C_E);
    int val[C_E], bb[C_E], loc[C_E];
    #pragma unroll
    for (int i = 0; i < C_E; ++i){
        int e = base + i*C_T + threadIdx.x;
        bb[i] = -1;
        if (e < NE){
            int s, d;
            if (f){ s = (int)((const long long*)edges)[e]; d = (int)((const long long*)edges)[NE + e]; }
            else  { s = ((const int*)edges)[e];            d = ((const int*)edges)[NE + e]; }
            val[i] = (s << 8) | (d & 255);
            bb[i]  = d >> 8;
            loc[i] = atomicAdd(&hist[bb[i]], 1);
        }
    }
    __syncthreads();
    for (int i = threadIdx.x; i < NBUK; i += C_T){
        int c = hist[i];
        gbase[i] = c ? atomicAdd(&bcur[i], c) : 0;
    }
    __syncthreads();
    #pragma unroll
    for (int i = 0; i < C_E; ++i){
        if (bb[i] >= 0) ebuf[gbase[bb[i]] + loc[i]] = val[i];
    }
}

// ---------------- per-bucket degree -> dinv (LDS only) ----------------
__global__ __launch_bounds__(256) void k_deg(const int* __restrict__ bptr, const int* __restrict__ ebuf,
                                             float* __restrict__ dinv){
    __shared__ int cnt[256];
    cnt[threadIdx.x] = 0;
    __syncthreads();
    const int b = blockIdx.x;
    for (int e = bptr[b] + threadIdx.x; e < bptr[b+1]; e += 256)
        atomicAdd(&cnt[ebuf[e] & 255], 1);
    __syncthreads();
    int v = b*256 + threadIdx.x;
    if (v < NN) dinv[v] = rsqrtf((float)(cnt[threadIdx.x] + 1));
}

// ---------------- GEMM1: h1s = (x @ W1) * dinv[row], [NN][32] ----------------
__global__ __launch_bounds__(256) void k_gemm1(const float* __restrict__ x, const float* __restrict__ W1,
                                               const float* __restrict__ dinv, float* __restrict__ h1s){
    __shared__ float xt[256][33];
    __shared__ float wt[32][32];
    const int tid = threadIdx.x;
    const int row0 = blockIdx.x * 256;
    const int cg = tid & 7;
    const int rg = tid >> 3;
    float acc[8][4];
    #pragma unroll
    for (int i = 0; i < 8; ++i){ acc[i][0]=0.f; acc[i][1]=0.f; acc[i][2]=0.f; acc[i][3]=0.f; }

    for (int k0 = 0; k0 < INF; k0 += 32){
        {
            int kk = tid >> 3, c4 = (tid & 7) * 4;
            *(float4*)&wt[kk][c4] = *(const float4*)&W1[(k0 + kk)*HID + c4];
        }
        #pragma unroll
        for (int l = 0; l < 8; ++l){
            int idx4 = l*256 + tid;
            int r = idx4 >> 3, c4 = idx4 & 7;
            int grow = row0 + r;
            float4 v = make_float4(0.f, 0.f, 0.f, 0.f);
            if (grow < NN) v = *(const float4*)&x[(size_t)grow*INF + k0 + c4*4];
            float* dst = &xt[r][c4*4];
            dst[0]=v.x; dst[1]=v.y; dst[2]=v.z; dst[3]=v.w;
        }
        __syncthreads();
        for (int k = 0; k < 32; ++k){
            float4 w = *(const float4*)&wt[k][cg*4];
            #pragma unroll
            for (int i = 0; i < 8; ++i){
                float xv = xt[rg*8 + i][k];
                acc[i][0] = fmaf(xv, w.x, acc[i][0]);
                acc[i][1] = fmaf(xv, w.y, acc[i][1]);
                acc[i][2] = fmaf(xv, w.z, acc[i][2]);
                acc[i][3] = fmaf(xv, w.w, acc[i][3]);
            }
        }
        __syncthreads();
    }
    #pragma unroll
    for (int i = 0; i < 8; ++i){
        int r = row0 + rg*8 + i;
        if (r < NN){
            float d = dinv[r];
            float4 o; o.x=acc[i][0]*d; o.y=acc[i][1]*d; o.z=acc[i][2]*d; o.w=acc[i][3]*d;
            *(float4*)&h1s[(size_t)r*HID + cg*4] = o;
        }
    }
}

// ---------------- Aggregation 1 in LDS + bias + ReLU (one block per bucket) ----------------
__global__ __launch_bounds__(1024) void k_agg1(const float* __restrict__ h1s, const int* __restrict__ bptr,
                                               const int* __restrict__ ebuf, const float* __restrict__ dinv,
                                               const float* __restrict__ b1, float* __restrict__ relu1){
    __shared__ float acc[256*HID];   // 32 KB
    const int b = blockIdx.x, tid = threadIdx.x, v0 = b*256;
    for (int i = tid; i < 256*HID; i += 1024){
        int v = v0 + (i >> 5);
        acc[i] = (v < NN) ? h1s[(size_t)v0*HID + i] : 0.f;   // self-loop term
    }
    __syncthreads();
    const int lane = tid & 31, g = tid >> 5;    // 32 groups of 32 lanes
    const int beg = bptr[b], nE = bptr[b+1] - beg;
    for (int t0 = g*32; t0 < nE; t0 += 32*32){
        int rem = nE - t0;
        int cnt = rem < 32 ? rem : 32;
        int ev = (lane < cnt) ? ebuf[beg + t0 + lane] : 0;
        if (cnt == 32){
            #pragma unroll 8
            for (int j = 0; j < 32; ++j){
                int e = __shfl(ev, j, 32);
                float vv = h1s[(size_t)(e >> 8)*HID + lane];
                atomicAdd(&acc[(e & 255)*HID + lane], vv);
            }
        } else {
            for (int j = 0; j < cnt; ++j){
                int e = __shfl(ev, j, 32);
                float vv = h1s[(size_t)(e >> 8)*HID + lane];
                atomicAdd(&acc[(e & 255)*HID + lane], vv);
            }
        }
    }
    __syncthreads();
    for (int i = tid; i < 256*HID; i += 1024){
        int v = v0 + (i >> 5);
        if (v < NN){
            float r = dinv[v]*acc[i] + b1[i & 31];
            relu1[(size_t)v0*HID + i] = fmaxf(r, 0.f);   // FIXED: flat bucket offset, was v*HID+i
        }
    }
}

// ---------------- pad W2 [32][7] -> [32][8] ----------------
__global__ void k_padW2(const float* __restrict__ W2, float* __restrict__ w2p){
    int t = threadIdx.x;
    int k = t >> 3, j = t & 7;
    w2p[t] = (j < NC) ? W2[k*NC + j] : 0.f;
}

// ---------------- GEMM2: h2s = (relu1 @ W2pad) * dinv[row], [NN][8] ----------------
__global__ __launch_bounds__(256) void k_gemm2(const float* __restrict__ relu1, const float* __restrict__ w2p,
                                               const float* __restrict__ dinv, float* __restrict__ h2s){
    __shared__ float w2s[256];
    w2s[threadIdx.x] = w2p[threadIdx.x];
    __syncthreads();
    int r = blockIdx.x*256 + threadIdx.x;
    if (r >= NN) return;
    float rv[HID];
    #pragma unroll
    for (int q = 0; q < 8; ++q){
        float4 t = *(const float4*)&relu1[(size_t)r*HID + q*4];
        rv[q*4]=t.x; rv[q*4+1]=t.y; rv[q*4+2]=t.z; rv[q*4+3]=t.w;
    }
    float acc[8] = {0.f,0.f,0.f,0.f,0.f,0.f,0.f,0.f};
    #pragma unroll
    for (int k = 0; k < HID; ++k){
        #pragma unroll
        for (int j = 0; j < 8; ++j) acc[j] = fmaf(rv[k], w2s[k*8 + j], acc[j]);
    }
    float d = dinv[r];
    float4 o0; o0.x=acc[0]*d; o0.y=acc[1]*d; o0.z=acc[2]*d; o0.w=acc[3]*d;
    float4 o1; o1.x=acc[4]*d; o1.y=acc[5]*d; o1.z=acc[6]*d; o1.w=acc[7]*d;
    *(float4*)&h2s[(size_t)r*8]     = o0;
    *(float4*)&h2s[(size_t)r*8 + 4] = o1;
}

// ---------------- Aggregation 2 in LDS + bias + softmax (one block per bucket) ----------------
__global__ __launch_bounds__(1024) void k_agg2(const float* __restrict__ h2s, const int* __restrict__ bptr,
                                               const int* __restrict__ ebuf, const float* __restrict__ dinv,
                                               const float* __restrict__ b2, float* __restrict__ out){
    __shared__ float acc[256*8];     // 8 KB
    const int b = blockIdx.x, tid = threadIdx.x, v0 = b*256;
    for (int i = tid; i < 2048; i += 1024){
        int v = v0 + (i >> 3);
        acc[i] = (v < NN) ? h2s[(size_t)v0*8 + i] : 0.f;     // self-loop term
    }
    __syncthreads();
    const int lane = tid & 7, g = tid >> 3;   // 128 groups of 8 lanes
    const int beg = bptr[b], nE = bptr[b+1] - beg;
    for (int t0 = g*8; t0 < nE; t0 += 128*8){
        int rem = nE - t0;
        int cnt = rem < 8 ? rem : 8;
        int ev = (lane < cnt) ? ebuf[beg + t0 + lane] : 0;
        if (cnt == 8){
            #pragma unroll
            for (int j = 0; j < 8; ++j){
                int e = __shfl(ev, j, 8);
                float vv = h2s[(size_t)(e >> 8)*8 + lane];
                atomicAdd(&acc[(e & 255)*8 + lane], vv);
            }
        } else {
            for (int j = 0; j < cnt; ++j){
                int e = __shfl(ev, j, 8);
                float vv = h2s[(size_t)(e >> 8)*8 + lane];
                atomicAdd(&acc[(e & 255)*8 + lane], vv);
            }
        }
    }
    __syncthreads();
    // softmax: 8 lanes per node, each group handles 2 nodes
    #pragma unroll
    for (int r = 0; r < 2; ++r){
        int vl = g*2 + r;
        int v = v0 + vl;
        if (v < NN){
            float logit = (lane < NC) ? (dinv[v]*acc[vl*8 + lane] + b2[lane]) : -INFINITY;
            float m = logit;
            #pragma unroll
            for (int off = 1; off < 8; off <<= 1) m = fmaxf(m, __shfl_xor(m, off, 8));
            float ex = __expf(logit - m);
            float s = ex;
            #pragma unroll
            for (int off = 1; off < 8; off <<= 1) s += __shfl_xor(s, off, 8);
            if (lane < NC) out[(size_t)v*NC + lane] = ex / s;
        }
    }
}

extern "C" void kernel_launch(void* const* d_in, const int* in_sizes, int n_in,
                              void* d_out, int out_size, void* d_ws, size_t ws_size,
                              hipStream_t stream){
    const float* x  = (const float*)d_in[0];
    const void*  ei = d_in[1];
    const float* W1 = (const float*)d_in[2];
    const float* b1 = (const float*)d_in[3];
    const float* W2 = (const float*)d_in[4];
    const float* b2 = (const float*)d_in[5];
    float* out = (float*)d_out;

    char* ws = (char*)d_ws;
    size_t off = 0;
    auto alloc = [&](size_t bytes)->char*{
        char* p = ws + off; off += (bytes + 255) & ~(size_t)255; return p;
    };
    int*   ebuf  = (int*)  alloc((size_t)NE*4);
    int*   bhist = (int*)  alloc((size_t)(NBUK+1)*4);
    int*   bptr  = (int*)  alloc((size_t)(NBUK+1)*4);
    int*   bcur  = (int*)  alloc((size_t)(NBUK+1)*4);
    int*   flag  = (int*)  alloc(4);
    float* dinv  = (float*)alloc((size_t)NN*4);
    float* h1s   = (float*)alloc((size_t)NN*HID*4);
    float* relu1 = (float*)alloc((size_t)NN*HID*4);
    float* h2s   = (float*)alloc((size_t)NN*8*4);
    float* w2p   = (float*)alloc(256*4);

    const int NB = (NN + 255)/256;                 // 391
    const int SB = (NE + C_T*C_E - 1)/(C_T*C_E);   // 391

    hipMemsetAsync(bhist, 0, (size_t)(NBUK+1)*4, stream);
    k_detect <<<1, 256, 0, stream>>>((const unsigned*)ei, flag);
    k_bhist  <<<1024, 256, 0, stream>>>(ei, flag, bhist);
    k_bscan  <<<1, 512, 0, stream>>>(bhist, bptr, bcur);
    k_scatter<<<SB, C_T, 0, stream>>>(ei, flag, bcur, ebuf);
    k_deg    <<<NBUK, 256, 0, stream>>>(bptr, ebuf, dinv);
    k_gemm1  <<<NB, 256, 0, stream>>>(x, W1, dinv, h1s);
    k_agg1   <<<NBUK, 1024, 0, stream>>>(h1s, bptr, ebuf, dinv, b1, relu1);
    k_padW2  <<<1, 256, 0, stream>>>(W2, w2p);
    k_gemm2  <<<NB, 256, 0, stream>>>(relu1, w2p, dinv, h2s);
    k_agg2   <<<NBUK, 1024, 0, stream>>>(h2s, bptr, ebuf, dinv, b2, out);
}

// Round 4
// 320.558 us; speedup vs baseline: 3.3840x; 3.3840x over previous
//
#include <hip/hip_runtime.h>
#include <hip/hip_fp16.h>
#include <math.h>

#define NN 100000      // nodes
#define NE 3200000     // edges
#define INF 512        // in feat
#define HID 32         // hidden
#define NC 7           // classes
#define NBUK 391       // ceil(NN/256) node buckets of 256

// ---------------- dtype detection: int64 (flag=1) vs int32 (flag=0) ----------------
__global__ void k_detect(const unsigned* __restrict__ edges, int* __restrict__ flag){
    __shared__ int nz;
    if (threadIdx.x == 0) nz = 0;
    __syncthreads();
    if (edges[2*threadIdx.x + 1] != 0u) atomicOr(&nz, 1);
    __syncthreads();
    if (threadIdx.x == 0) *flag = (nz == 0) ? 1 : 0;
}

// ---------------- bucket histogram (LDS-aggregated) ----------------
__global__ __launch_bounds__(256) void k_bhist(const void* __restrict__ edges, const int* __restrict__ flag,
                                               int* __restrict__ bhist){
    __shared__ int h[NBUK];
    for (int i = threadIdx.x; i < NBUK; i += 256) h[i] = 0;
    __syncthreads();
    const bool f = (*flag != 0);
    const int stride = gridDim.x * 256;
    for (int e = blockIdx.x*256 + threadIdx.x; e < NE; e += stride){
        int d = f ? (int)((const long long*)edges)[NE + e] : ((const int*)edges)[NE + e];
        atomicAdd(&h[d >> 8], 1);
    }
    __syncthreads();
    for (int i = threadIdx.x; i < NBUK; i += 256) if (h[i]) atomicAdd(&bhist[i], h[i]);
}

// ---------------- scan buckets (single block) ----------------
__global__ __launch_bounds__(512) void k_bscan(const int* __restrict__ bhist, int* __restrict__ bptr,
                                               int* __restrict__ bcur){
    __shared__ int sd[512];
    int t = threadIdx.x;
    int v = (t < NBUK) ? bhist[t] : 0;
    sd[t] = v;
    __syncthreads();
    for (int off = 1; off < 512; off <<= 1){
        int a = (t >= off) ? sd[t - off] : 0;
        __syncthreads();
        sd[t] += a;
        __syncthreads();
    }
    if (t < NBUK){ bptr[t] = sd[t] - v; bcur[t] = sd[t] - v; }
    if (t == 0) bptr[NBUK] = NE;
}

// ---------------- block-aggregated bucket scatter: ebuf = (src<<8)|dst_local ----------------
#define C_T 512
#define C_E 16
__global__ __launch_bounds__(C_T) void k_scatter(const void* __restrict__ edges, const int* __restrict__ flag,
                                                 int* __restrict__ bcur, int* __restrict__ ebuf){
    __shared__ int hist[NBUK];
    __shared__ int gbase[NBUK];
    for (int i = threadIdx.x; i < NBUK; i += C_T) hist[i] = 0;
    __syncthreads();
    const bool f = (*flag != 0);
    const int base = blockIdx.x * (C_T * C_E);
    int val[C_E], bb[C_E], loc[C_E];
    #pragma unroll
    for (int i = 0; i < C_E; ++i){
        int e = base + i*C_T + threadIdx.x;
        bb[i] = -1;
        if (e < NE){
            int s, d;
            if (f){ s = (int)((const long long*)edges)[e]; d = (int)((const long long*)edges)[NE + e]; }
            else  { s = ((const int*)edges)[e];            d = ((const int*)edges)[NE + e]; }
            val[i] = (s << 8) | (d & 255);
            bb[i]  = d >> 8;
            loc[i] = atomicAdd(&hist[bb[i]], 1);
        }
    }
    __syncthreads();
    for (int i = threadIdx.x; i < NBUK; i += C_T){
        int c = hist[i];
        gbase[i] = c ? atomicAdd(&bcur[i], c) : 0;
    }
    __syncthreads();
    #pragma unroll
    for (int i = 0; i < C_E; ++i){
        if (bb[i] >= 0) ebuf[gbase[bb[i]] + loc[i]] = val[i];
    }
}

// ---------------- per-bucket exact CSR + row_ptr + dinv ----------------
__global__ __launch_bounds__(256) void k_csr(const int* __restrict__ bptr, const int* __restrict__ ebuf,
                                             int* __restrict__ rowp, int* __restrict__ csr,
                                             float* __restrict__ dinv){
    __shared__ int cnt[256];
    __shared__ int sd[256];
    __shared__ int cur[256];
    const int b = blockIdx.x, t = threadIdx.x;
    const int beg = bptr[b], nE = bptr[b+1] - beg;
    cnt[t] = 0;
    __syncthreads();
    for (int i = t; i < nE; i += 256) atomicAdd(&cnt[ebuf[beg+i] & 255], 1);
    __syncthreads();
    int c = cnt[t];
    sd[t] = c;
    __syncthreads();
    for (int off = 1; off < 256; off <<= 1){
        int a = (t >= off) ? sd[t-off] : 0;
        __syncthreads();
        sd[t] += a;
        __syncthreads();
    }
    int ex = sd[t] - c;          // exclusive prefix within bucket
    cur[t] = ex;
    int v = b*256 + t;
    if (v < NN){
        rowp[v] = beg + ex;
        dinv[v] = rsqrtf((float)(c + 1));     // +1 self-loop
        if (v == NN-1) rowp[NN] = beg + ex + c;
    }
    __syncthreads();
    for (int i = t; i < nE; i += 256){
        int e = ebuf[beg+i];
        int p = atomicAdd(&cur[e & 255], 1);
        csr[beg + p] = e >> 8;   // src node id
    }
}

// ---------------- GEMM1: h1s = fp16((x @ W1) * dinv[row]), [NN][32] ----------------
__global__ __launch_bounds__(256) void k_gemm1(const float* __restrict__ x, const float* __restrict__ W1,
                                               const float* __restrict__ dinv, __half* __restrict__ h1s){
    __shared__ float xt[256][33];
    __shared__ float wt[32][32];
    const int tid = threadIdx.x;
    const int row0 = blockIdx.x * 256;
    const int cg = tid & 7;
    const int rg = tid >> 3;
    float acc[8][4];
    #pragma unroll
    for (int i = 0; i < 8; ++i){ acc[i][0]=0.f; acc[i][1]=0.f; acc[i][2]=0.f; acc[i][3]=0.f; }

    for (int k0 = 0; k0 < INF; k0 += 32){
        {
            int kk = tid >> 3, c4 = (tid & 7) * 4;
            *(float4*)&wt[kk][c4] = *(const float4*)&W1[(k0 + kk)*HID + c4];
        }
        #pragma unroll
        for (int l = 0; l < 8; ++l){
            int idx4 = l*256 + tid;
            int r = idx4 >> 3, c4 = idx4 & 7;
            int grow = row0 + r;
            float4 v = make_float4(0.f, 0.f, 0.f, 0.f);
            if (grow < NN) v = *(const float4*)&x[(size_t)grow*INF + k0 + c4*4];
            float* dst = &xt[r][c4*4];
            dst[0]=v.x; dst[1]=v.y; dst[2]=v.z; dst[3]=v.w;
        }
        __syncthreads();
        for (int k = 0; k < 32; ++k){
            float4 w = *(const float4*)&wt[k][cg*4];
            #pragma unroll
            for (int i = 0; i < 8; ++i){
                float xv = xt[rg*8 + i][k];
                acc[i][0] = fmaf(xv, w.x, acc[i][0]);
                acc[i][1] = fmaf(xv, w.y, acc[i][1]);
                acc[i][2] = fmaf(xv, w.z, acc[i][2]);
                acc[i][3] = fmaf(xv, w.w, acc[i][3]);
            }
        }
        __syncthreads();
    }
    #pragma unroll
    for (int i = 0; i < 8; ++i){
        int r = row0 + rg*8 + i;
        if (r < NN){
            float d = dinv[r];
            union { __half2 h[2]; float2 f; } u;
            u.h[0] = __floats2half2_rn(acc[i][0]*d, acc[i][1]*d);
            u.h[1] = __floats2half2_rn(acc[i][2]*d, acc[i][3]*d);
            *(float2*)&h1s[(size_t)r*HID + cg*4] = u.f;
        }
    }
}

// ---------------- Aggregation 1: 32 lanes/node, 4-way MLP, bias+ReLU ----------------
__global__ __launch_bounds__(256) void k_agg1(const __half* __restrict__ h1s, const int* __restrict__ rowp,
                                              const int* __restrict__ csr, const float* __restrict__ dinv,
                                              const float* __restrict__ b1, float* __restrict__ relu1){
    const int lane = threadIdx.x & 31;
    const int v = blockIdx.x*8 + (threadIdx.x >> 5);
    if (v >= NN) return;
    float acc0 = __half2float(h1s[(size_t)v*HID + lane]);   // self-loop term
    float acc1 = 0.f, acc2 = 0.f, acc3 = 0.f;
    const int beg = rowp[v], end = rowp[v+1];
    int e = beg;
    for (; e + 4 <= end; e += 4){
        int s0 = csr[e], s1 = csr[e+1], s2 = csr[e+2], s3 = csr[e+3];
        acc0 += __half2float(h1s[(size_t)s0*HID + lane]);
        acc1 += __half2float(h1s[(size_t)s1*HID + lane]);
        acc2 += __half2float(h1s[(size_t)s2*HID + lane]);
        acc3 += __half2float(h1s[(size_t)s3*HID + lane]);
    }
    for (; e < end; ++e)
        acc0 += __half2float(h1s[(size_t)csr[e]*HID + lane]);
    float r = dinv[v]*((acc0 + acc1) + (acc2 + acc3)) + b1[lane];
    relu1[(size_t)v*HID + lane] = fmaxf(r, 0.f);
}

// ---------------- pad W2 [32][7] -> [32][8] ----------------
__global__ void k_padW2(const float* __restrict__ W2, float* __restrict__ w2p){
    int t = threadIdx.x;
    int k = t >> 3, j = t & 7;
    w2p[t] = (j < NC) ? W2[k*NC + j] : 0.f;
}

// ---------------- GEMM2: h2s = fp16((relu1 @ W2pad) * dinv[row]), [NN][8] ----------------
__global__ __launch_bounds__(256) void k_gemm2(const float* __restrict__ relu1, const float* __restrict__ w2p,
                                               const float* __restrict__ dinv, __half* __restrict__ h2s){
    __shared__ float w2s[256];
    w2s[threadIdx.x] = w2p[threadIdx.x];
    __syncthreads();
    int r = blockIdx.x*256 + threadIdx.x;
    if (r >= NN) return;
    float rv[HID];
    #pragma unroll
    for (int q = 0; q < 8; ++q){
        float4 t = *(const float4*)&relu1[(size_t)r*HID + q*4];
        rv[q*4]=t.x; rv[q*4+1]=t.y; rv[q*4+2]=t.z; rv[q*4+3]=t.w;
    }
    float acc[8] = {0.f,0.f,0.f,0.f,0.f,0.f,0.f,0.f};
    #pragma unroll
    for (int k = 0; k < HID; ++k){
        #pragma unroll
        for (int j = 0; j < 8; ++j) acc[j] = fmaf(rv[k], w2s[k*8 + j], acc[j]);
    }
    float d = dinv[r];
    union { __half2 h[4]; float4 f; } u;
    u.h[0] = __floats2half2_rn(acc[0]*d, acc[1]*d);
    u.h[1] = __floats2half2_rn(acc[2]*d, acc[3]*d);
    u.h[2] = __floats2half2_rn(acc[4]*d, acc[5]*d);
    u.h[3] = __floats2half2_rn(acc[6]*d, acc[7]*d);
    *(float4*)&h2s[(size_t)r*8] = u.f;
}

// ---------------- Aggregation 2: 32 lanes/node (4 edges x 8 feats), bias+softmax ----------------
__global__ __launch_bounds__(256) void k_agg2(const __half* __restrict__ h2s, const int* __restrict__ rowp,
                                              const int* __restrict__ csr, const float* __restrict__ dinv,
                                              const float* __restrict__ b2, float* __restrict__ out){
    const int lane = threadIdx.x & 31;
    const int v = blockIdx.x*8 + (threadIdx.x >> 5);
    if (v >= NN) return;
    const int f = lane & 7, sub = lane >> 3;   // 4 sub-groups handle interleaved edges
    float acc = 0.f;
    const int beg = rowp[v], end = rowp[v+1];
    for (int e = beg + sub; e < end; e += 4){
        int s = csr[e];
        acc += __half2float(h2s[(size_t)s*8 + f]);
    }
    // reduce the 4 sub-group partials (lanes differing in bits 3,4)
    acc += __shfl_xor(acc, 8, 32);
    acc += __shfl_xor(acc, 16, 32);
    acc += __half2float(h2s[(size_t)v*8 + f]);   // self-loop term
    float logit = (f < NC) ? (dinv[v]*acc + b2[f]) : -INFINITY;
    float m = logit;
    #pragma unroll
    for (int off = 1; off < 8; off <<= 1) m = fmaxf(m, __shfl_xor(m, off, 8));
    float ex = __expf(logit - m);
    float s = ex;
    #pragma unroll
    for (int off = 1; off < 8; off <<= 1) s += __shfl_xor(s, off, 8);
    if (sub == 0 && f < NC) out[(size_t)v*NC + f] = ex / s;
}

extern "C" void kernel_launch(void* const* d_in, const int* in_sizes, int n_in,
                              void* d_out, int out_size, void* d_ws, size_t ws_size,
                              hipStream_t stream){
    const float* x  = (const float*)d_in[0];
    const void*  ei = d_in[1];
    const float* W1 = (const float*)d_in[2];
    const float* b1 = (const float*)d_in[3];
    const float* W2 = (const float*)d_in[4];
    const float* b2 = (const float*)d_in[5];
    float* out = (float*)d_out;

    char* ws = (char*)d_ws;
    size_t off = 0;
    auto alloc = [&](size_t bytes)->char*{
        char* p = ws + off; off += (bytes + 255) & ~(size_t)255; return p;
    };
    int*    ebuf  = (int*)   alloc((size_t)NE*4);
    int*    csr   = (int*)   alloc((size_t)NE*4);
    int*    bhist = (int*)   alloc((size_t)(NBUK+1)*4);
    int*    bptr  = (int*)   alloc((size_t)(NBUK+1)*4);
    int*    bcur  = (int*)   alloc((size_t)(NBUK+1)*4);
    int*    flag  = (int*)   alloc(4);
    int*    rowp  = (int*)   alloc((size_t)(NN+1)*4);
    float*  dinv  = (float*) alloc((size_t)NN*4);
    __half* h1s   = (__half*)alloc((size_t)NN*HID*2);
    float*  relu1 = (float*) alloc((size_t)NN*HID*4);
    __half* h2s   = (__half*)alloc((size_t)NN*8*2);
    float*  w2p   = (float*) alloc(256*4);

    const int NB = (NN + 255)/256;                 // 391
    const int SB = (NE + C_T*C_E - 1)/(C_T*C_E);   // 391

    hipMemsetAsync(bhist, 0, (size_t)(NBUK+1)*4, stream);
    k_detect <<<1, 256, 0, stream>>>((const unsigned*)ei, flag);
    k_bhist  <<<1024, 256, 0, stream>>>(ei, flag, bhist);
    k_bscan  <<<1, 512, 0, stream>>>(bhist, bptr, bcur);
    k_scatter<<<SB, C_T, 0, stream>>>(ei, flag, bcur, ebuf);
    k_csr    <<<NBUK, 256, 0, stream>>>(bptr, ebuf, rowp, csr, dinv);
    k_gemm1  <<<NB, 256, 0, stream>>>(x, W1, dinv, h1s);
    k_agg1   <<<NN/8, 256, 0, stream>>>(h1s, rowp, csr, dinv, b1, relu1);
    k_padW2  <<<1, 256, 0, stream>>>(W2, w2p);
    k_gemm2  <<<NB, 256, 0, stream>>>(relu1, w2p, dinv, h2s);
    k_agg2   <<<NN/8, 256, 0, stream>>>(h2s, rowp, csr, dinv, b2, out);
}

// Round 5
// 265.539 us; speedup vs baseline: 4.0852x; 1.2072x over previous
//
#include <hip/hip_runtime.h>
#include <hip/hip_fp16.h>
#include <math.h>

#define NN 100000      // nodes
#define NE 3200000     // edges
#define INF 512        // in feat
#define HID 32         // hidden
#define NC 7           // classes
#define NBUK 391       // ceil(NN/256) node buckets of 256

// ---------------- dtype detection: int64 (flag=1) vs int32 (flag=0) ----------------
__global__ void k_detect(const unsigned* __restrict__ edges, int* __restrict__ flag){
    __shared__ int nz;
    if (threadIdx.x == 0) nz = 0;
    __syncthreads();
    if (edges[2*threadIdx.x + 1] != 0u) atomicOr(&nz, 1);
    __syncthreads();
    if (threadIdx.x == 0) *flag = (nz == 0) ? 1 : 0;
}

// ---------------- bucket histogram (LDS-aggregated) ----------------
__global__ __launch_bounds__(256) void k_bhist(const void* __restrict__ edges, const int* __restrict__ flag,
                                               int* __restrict__ bhist){
    __shared__ int h[NBUK];
    for (int i = threadIdx.x; i < NBUK; i += 256) h[i] = 0;
    __syncthreads();
    const bool f = (*flag != 0);
    const int stride = gridDim.x * 256;
    for (int e = blockIdx.x*256 + threadIdx.x; e < NE; e += stride){
        int d = f ? (int)((const long long*)edges)[NE + e] : ((const int*)edges)[NE + e];
        atomicAdd(&h[d >> 8], 1);
    }
    __syncthreads();
    for (int i = threadIdx.x; i < NBUK; i += 256) if (h[i]) atomicAdd(&bhist[i], h[i]);
}

// ---------------- scan buckets (single block) ----------------
__global__ __launch_bounds__(512) void k_bscan(const int* __restrict__ bhist, int* __restrict__ bptr,
                                               int* __restrict__ bcur){
    __shared__ int sd[512];
    int t = threadIdx.x;
    int v = (t < NBUK) ? bhist[t] : 0;
    sd[t] = v;
    __syncthreads();
    for (int off = 1; off < 512; off <<= 1){
        int a = (t >= off) ? sd[t - off] : 0;
        __syncthreads();
        sd[t] += a;
        __syncthreads();
    }
    if (t < NBUK){ bptr[t] = sd[t] - v; bcur[t] = sd[t] - v; }
    if (t == 0) bptr[NBUK] = NE;
}

// ---------------- block-aggregated bucket scatter: ebuf = (src<<8)|dst_local ----------------
#define C_T 512
#define C_E 16
__global__ __launch_bounds__(C_T) void k_scatter(const void* __restrict__ edges, const int* __restrict__ flag,
                                                 int* __restrict__ bcur, int* __restrict__ ebuf){
    __shared__ int hist[NBUK];
    __shared__ int gbase[NBUK];
    for (int i = threadIdx.x; i < NBUK; i += C_T) hist[i] = 0;
    __syncthreads();
    const bool f = (*flag != 0);
    const int base = blockIdx.x * (C_T * C_E);
    int val[C_E], bb[C_E], loc[C_E];
    #pragma unroll
    for (int i = 0; i < C_E; ++i){
        int e = base + i*C_T + threadIdx.x;
        bb[i] = -1;
        if (e < NE){
            int s, d;
            if (f){ s = (int)((const long long*)edges)[e]; d = (int)((const long long*)edges)[NE + e]; }
            else  { s = ((const int*)edges)[e];            d = ((const int*)edges)[NE + e]; }
            val[i] = (s << 8) | (d & 255);
            bb[i]  = d >> 8;
            loc[i] = atomicAdd(&hist[bb[i]], 1);
        }
    }
    __syncthreads();
    for (int i = threadIdx.x; i < NBUK; i += C_T){
        int c = hist[i];
        gbase[i] = c ? atomicAdd(&bcur[i], c) : 0;
    }
    __syncthreads();
    #pragma unroll
    for (int i = 0; i < C_E; ++i){
        if (bb[i] >= 0) ebuf[gbase[bb[i]] + loc[i]] = val[i];
    }
}

// ---------------- per-bucket exact CSR + row_ptr + dinv ----------------
__global__ __launch_bounds__(256) void k_csr(const int* __restrict__ bptr, const int* __restrict__ ebuf,
                                             int* __restrict__ rowp, int* __restrict__ csr,
                                             float* __restrict__ dinv){
    __shared__ int cnt[256];
    __shared__ int sd[256];
    __shared__ int cur[256];
    const int b = blockIdx.x, t = threadIdx.x;
    const int beg = bptr[b], nE = bptr[b+1] - beg;
    cnt[t] = 0;
    __syncthreads();
    for (int i = t; i < nE; i += 256) atomicAdd(&cnt[ebuf[beg+i] & 255], 1);
    __syncthreads();
    int c = cnt[t];
    sd[t] = c;
    __syncthreads();
    for (int off = 1; off < 256; off <<= 1){
        int a = (t >= off) ? sd[t-off] : 0;
        __syncthreads();
        sd[t] += a;
        __syncthreads();
    }
    int ex = sd[t] - c;          // exclusive prefix within bucket
    cur[t] = ex;
    int v = b*256 + t;
    if (v < NN){
        rowp[v] = beg + ex;
        dinv[v] = rsqrtf((float)(c + 1));     // +1 self-loop
        if (v == NN-1) rowp[NN] = beg + ex + c;
    }
    __syncthreads();
    for (int i = t; i < nE; i += 256){
        int e = ebuf[beg+i];
        int p = atomicAdd(&cur[e & 255], 1);
        csr[beg + p] = e >> 8;   // src node id
    }
}

// ---------------- GEMM1: h1s = fp16((x @ W1) * dinv[row]), [NN][32] ----------------
// 64-row tiles (grid 1563) for occupancy; 2 rows x 4 cols per thread.
__global__ __launch_bounds__(256) void k_gemm1(const float* __restrict__ x, const float* __restrict__ W1,
                                               const float* __restrict__ dinv, __half* __restrict__ h1s){
    __shared__ float xt[64][36];   // stride 36: 16B-aligned float4, 2-way-free banks
    __shared__ float wt[32][32];
    const int tid = threadIdx.x;
    const int row0 = blockIdx.x * 64;
    const int cg = tid & 7;        // col group: cols cg*4..cg*4+3
    const int rp = tid >> 3;       // row pair: rows 2rp, 2rp+1
    float acc[2][4];
    #pragma unroll
    for (int i = 0; i < 2; ++i){ acc[i][0]=0.f; acc[i][1]=0.f; acc[i][2]=0.f; acc[i][3]=0.f; }

    for (int k0 = 0; k0 < INF; k0 += 32){
        { // W tile 32x32
            int kk = tid >> 3, c4 = (tid & 7) * 4;
            *(float4*)&wt[kk][c4] = *(const float4*)&W1[(k0 + kk)*HID + c4];
        }
        #pragma unroll
        for (int l = 0; l < 2; ++l){ // x tile 64x32 = 512 float4, 2 per thread
            int idx = l*256 + tid;
            int rr = idx >> 3, f4 = idx & 7;
            int grow = row0 + rr;
            float4 v = make_float4(0.f, 0.f, 0.f, 0.f);
            if (grow < NN) v = *(const float4*)&x[(size_t)grow*INF + k0 + f4*4];
            *(float4*)&xt[rr][f4*4] = v;
        }
        __syncthreads();
        #pragma unroll
        for (int k = 0; k < 32; ++k){
            float4 w = *(const float4*)&wt[k][cg*4];
            float x0 = xt[2*rp][k];
            float x1 = xt[2*rp+1][k];
            acc[0][0] = fmaf(x0, w.x, acc[0][0]);
            acc[0][1] = fmaf(x0, w.y, acc[0][1]);
            acc[0][2] = fmaf(x0, w.z, acc[0][2]);
            acc[0][3] = fmaf(x0, w.w, acc[0][3]);
            acc[1][0] = fmaf(x1, w.x, acc[1][0]);
            acc[1][1] = fmaf(x1, w.y, acc[1][1]);
            acc[1][2] = fmaf(x1, w.z, acc[1][2]);
            acc[1][3] = fmaf(x1, w.w, acc[1][3]);
        }
        __syncthreads();
    }
    #pragma unroll
    for (int i = 0; i < 2; ++i){
        int r = row0 + 2*rp + i;
        if (r < NN){
            float d = dinv[r];
            union { __half2 h[2]; float2 f; } u;
            u.h[0] = __floats2half2_rn(acc[i][0]*d, acc[i][1]*d);
            u.h[1] = __floats2half2_rn(acc[i][2]*d, acc[i][3]*d);
            *(float2*)&h1s[(size_t)r*HID + cg*4] = u.f;
        }
    }
}

// ---------------- Aggregation 1: 32 lanes/node, 4-way MLP, bias+ReLU ----------------
__global__ __launch_bounds__(256) void k_agg1(const __half* __restrict__ h1s, const int* __restrict__ rowp,
                                              const int* __restrict__ csr, const float* __restrict__ dinv,
                                              const float* __restrict__ b1, float* __restrict__ relu1){
    const int lane = threadIdx.x & 31;
    const int v = blockIdx.x*8 + (threadIdx.x >> 5);
    if (v >= NN) return;
    float acc0 = __half2float(h1s[(size_t)v*HID + lane]);   // self-loop term
    float acc1 = 0.f, acc2 = 0.f, acc3 = 0.f;
    const int beg = rowp[v], end = rowp[v+1];
    int e = beg;
    for (; e + 4 <= end; e += 4){
        int s0 = csr[e], s1 = csr[e+1], s2 = csr[e+2], s3 = csr[e+3];
        acc0 += __half2float(h1s[(size_t)s0*HID + lane]);
        acc1 += __half2float(h1s[(size_t)s1*HID + lane]);
        acc2 += __half2float(h1s[(size_t)s2*HID + lane]);
        acc3 += __half2float(h1s[(size_t)s3*HID + lane]);
    }
    for (; e < end; ++e)
        acc0 += __half2float(h1s[(size_t)csr[e]*HID + lane]);
    float r = dinv[v]*((acc0 + acc1) + (acc2 + acc3)) + b1[lane];
    relu1[(size_t)v*HID + lane] = fmaxf(r, 0.f);
}

// ---------------- pad W2 [32][7] -> [32][8] ----------------
__global__ void k_padW2(const float* __restrict__ W2, float* __restrict__ w2p){
    int t = threadIdx.x;
    int k = t >> 3, j = t & 7;
    w2p[t] = (j < NC) ? W2[k*NC + j] : 0.f;
}

// ---------------- GEMM2: h2s = fp16((relu1 @ W2pad) * dinv[row]), [NN][8] ----------------
__global__ __launch_bounds__(256) void k_gemm2(const float* __restrict__ relu1, const float* __restrict__ w2p,
                                               const float* __restrict__ dinv, __half* __restrict__ h2s){
    __shared__ float w2s[256];
    w2s[threadIdx.x] = w2p[threadIdx.x];
    __syncthreads();
    int r = blockIdx.x*256 + threadIdx.x;
    if (r >= NN) return;
    float rv[HID];
    #pragma unroll
    for (int q = 0; q < 8; ++q){
        float4 t = *(const float4*)&relu1[(size_t)r*HID + q*4];
        rv[q*4]=t.x; rv[q*4+1]=t.y; rv[q*4+2]=t.z; rv[q*4+3]=t.w;
    }
    float acc[8] = {0.f,0.f,0.f,0.f,0.f,0.f,0.f,0.f};
    #pragma unroll
    for (int k = 0; k < HID; ++k){
        #pragma unroll
        for (int j = 0; j < 8; ++j) acc[j] = fmaf(rv[k], w2s[k*8 + j], acc[j]);
    }
    float d = dinv[r];
    union { __half2 h[4]; float4 f; } u;
    u.h[0] = __floats2half2_rn(acc[0]*d, acc[1]*d);
    u.h[1] = __floats2half2_rn(acc[2]*d, acc[3]*d);
    u.h[2] = __floats2half2_rn(acc[4]*d, acc[5]*d);
    u.h[3] = __floats2half2_rn(acc[6]*d, acc[7]*d);
    *(float4*)&h2s[(size_t)r*8] = u.f;
}

// ---------------- Aggregation 2: 32 lanes/node (4 edges x 8 feats), bias+softmax ----------------
__global__ __launch_bounds__(256) void k_agg2(const __half* __restrict__ h2s, const int* __restrict__ rowp,
                                              const int* __restrict__ csr, const float* __restrict__ dinv,
                                              const float* __restrict__ b2, float* __restrict__ out){
    const int lane = threadIdx.x & 31;
    const int v = blockIdx.x*8 + (threadIdx.x >> 5);
    if (v >= NN) return;
    const int f = lane & 7, sub = lane >> 3;   // 4 sub-groups handle interleaved edges
    float acc = 0.f;
    const int beg = rowp[v], end = rowp[v+1];
    for (int e = beg + sub; e < end; e += 4){
        int s = csr[e];
        acc += __half2float(h2s[(size_t)s*8 + f]);
    }
    // reduce the 4 sub-group partials (lanes differing in bits 3,4)
    acc += __shfl_xor(acc, 8, 32);
    acc += __shfl_xor(acc, 16, 32);
    acc += __half2float(h2s[(size_t)v*8 + f]);   // self-loop term
    float logit = (f < NC) ? (dinv[v]*acc + b2[f]) : -INFINITY;
    float m = logit;
    #pragma unroll
    for (int off = 1; off < 8; off <<= 1) m = fmaxf(m, __shfl_xor(m, off, 8));
    float ex = __expf(logit - m);
    float s = ex;
    #pragma unroll
    for (int off = 1; off < 8; off <<= 1) s += __shfl_xor(s, off, 8);
    if (sub == 0 && f < NC) out[(size_t)v*NC + f] = ex / s;
}

extern "C" void kernel_launch(void* const* d_in, const int* in_sizes, int n_in,
                              void* d_out, int out_size, void* d_ws, size_t ws_size,
                              hipStream_t stream){
    const float* x  = (const float*)d_in[0];
    const void*  ei = d_in[1];
    const float* W1 = (const float*)d_in[2];
    const float* b1 = (const float*)d_in[3];
    const float* W2 = (const float*)d_in[4];
    const float* b2 = (const float*)d_in[5];
    float* out = (float*)d_out;

    char* ws = (char*)d_ws;
    size_t off = 0;
    auto alloc = [&](size_t bytes)->char*{
        char* p = ws + off; off += (bytes + 255) & ~(size_t)255; return p;
    };
    int*    ebuf  = (int*)   alloc((size_t)NE*4);
    int*    csr   = (int*)   alloc((size_t)NE*4);
    int*    bhist = (int*)   alloc((size_t)(NBUK+1)*4);
    int*    bptr  = (int*)   alloc((size_t)(NBUK+1)*4);
    int*    bcur  = (int*)   alloc((size_t)(NBUK+1)*4);
    int*    flag  = (int*)   alloc(4);
    int*    rowp  = (int*)   alloc((size_t)(NN+1)*4);
    float*  dinv  = (float*) alloc((size_t)NN*4);
    __half* h1s   = (__half*)alloc((size_t)NN*HID*2);
    float*  relu1 = (float*) alloc((size_t)NN*HID*4);
    __half* h2s   = (__half*)alloc((size_t)NN*8*2);
    float*  w2p   = (float*) alloc(256*4);

    const int NB  = (NN + 255)/256;                 // 391
    const int G1B = (NN + 63)/64;                   // 1563
    const int SB  = (NE + C_T*C_E - 1)/(C_T*C_E);   // 391

    hipMemsetAsync(bhist, 0, (size_t)(NBUK+1)*4, stream);
    k_detect <<<1, 256, 0, stream>>>((const unsigned*)ei, flag);
    k_bhist  <<<1024, 256, 0, stream>>>(ei, flag, bhist);
    k_bscan  <<<1, 512, 0, stream>>>(bhist, bptr, bcur);
    k_scatter<<<SB, C_T, 0, stream>>>(ei, flag, bcur, ebuf);
    k_csr    <<<NBUK, 256, 0, stream>>>(bptr, ebuf, rowp, csr, dinv);
    k_gemm1  <<<G1B, 256, 0, stream>>>(x, W1, dinv, h1s);
    k_agg1   <<<NN/8, 256, 0, stream>>>(h1s, rowp, csr, dinv, b1, relu1);
    k_padW2  <<<1, 256, 0, stream>>>(W2, w2p);
    k_gemm2  <<<NB, 256, 0, stream>>>(relu1, w2p, dinv, h2s);
    k_agg2   <<<NN/8, 256, 0, stream>>>(h2s, rowp, csr, dinv, b2, out);
}

// Round 6
// 250.840 us; speedup vs baseline: 4.3246x; 1.0586x over previous
//
#include <hip/hip_runtime.h>
#include <hip/hip_fp16.h>
#include <math.h>

#define NN 100000      // nodes
#define NE 3200000     // edges
#define INF 512        // in feat
#define HID 32         // hidden
#define NC 7           // classes
#define NBUK 391       // ceil(NN/256) node buckets of 256

// Per-block int64-vs-int32 detection: first 256 int64 slots' hi words all zero <=> int64.
// Deterministic and identical across blocks (same data). Avoids a separate kernel.
#define DETECT_FLAG(edges, s_nz, f)                                            \
    if (threadIdx.x == 0) s_nz = 0;                                            \
    __syncthreads();                                                           \
    if (threadIdx.x < 256 && ((const unsigned*)(edges))[2*threadIdx.x + 1] != 0u) \
        atomicOr(&s_nz, 1);                                                    \
    __syncthreads();                                                           \
    const bool f = (s_nz == 0);

// ---------------- bucket histogram (LDS-aggregated) ----------------
__global__ __launch_bounds__(256) void k_bhist(const void* __restrict__ edges, int* __restrict__ bhist){
    __shared__ int h[NBUK];
    __shared__ int s_nz;
    for (int i = threadIdx.x; i < NBUK; i += 256) h[i] = 0;
    DETECT_FLAG(edges, s_nz, f)
    const int stride = gridDim.x * 256;
    for (int e = blockIdx.x*256 + threadIdx.x; e < NE; e += stride){
        int d = f ? (int)((const long long*)edges)[NE + e] : ((const int*)edges)[NE + e];
        atomicAdd(&h[d >> 8], 1);
    }
    __syncthreads();
    for (int i = threadIdx.x; i < NBUK; i += 256) if (h[i]) atomicAdd(&bhist[i], h[i]);
}

// ---------------- scan buckets (single block) ----------------
__global__ __launch_bounds__(512) void k_bscan(const int* __restrict__ bhist, int* __restrict__ bptr,
                                               int* __restrict__ bcur){
    __shared__ int sd[512];
    int t = threadIdx.x;
    int v = (t < NBUK) ? bhist[t] : 0;
    sd[t] = v;
    __syncthreads();
    for (int off = 1; off < 512; off <<= 1){
        int a = (t >= off) ? sd[t - off] : 0;
        __syncthreads();
        sd[t] += a;
        __syncthreads();
    }
    if (t < NBUK){ bptr[t] = sd[t] - v; bcur[t] = sd[t] - v; }
    if (t == 0) bptr[NBUK] = NE;
}

// ---------------- block-aggregated bucket scatter: ebuf = (src<<8)|dst_local ----------------
#define C_T 512
#define C_E 16
__global__ __launch_bounds__(C_T) void k_scatter(const void* __restrict__ edges,
                                                 int* __restrict__ bcur, int* __restrict__ ebuf){
    __shared__ int hist[NBUK];
    __shared__ int gbase[NBUK];
    __shared__ int s_nz;
    for (int i = threadIdx.x; i < NBUK; i += C_T) hist[i] = 0;
    DETECT_FLAG(edges, s_nz, f)
    const int base = blockIdx.x * (C_T * C_E);
    int val[C_E], bb[C_E], loc[C_E];
    #pragma unroll
    for (int i = 0; i < C_E; ++i){
        int e = base + i*C_T + threadIdx.x;
        bb[i] = -1;
        if (e < NE){
            int s, d;
            if (f){ s = (int)((const long long*)edges)[e]; d = (int)((const long long*)edges)[NE + e]; }
            else  { s = ((const int*)edges)[e];            d = ((const int*)edges)[NE + e]; }
            val[i] = (s << 8) | (d & 255);
            bb[i]  = d >> 8;
            loc[i] = atomicAdd(&hist[bb[i]], 1);
        }
    }
    __syncthreads();
    for (int i = threadIdx.x; i < NBUK; i += C_T){
        int c = hist[i];
        gbase[i] = c ? atomicAdd(&bcur[i], c) : 0;
    }
    __syncthreads();
    #pragma unroll
    for (int i = 0; i < C_E; ++i){
        if (bb[i] >= 0) ebuf[gbase[bb[i]] + loc[i]] = val[i];
    }
}

// ---------------- per-bucket exact CSR + row_ptr + dinv ----------------
__global__ __launch_bounds__(256) void k_csr(const int* __restrict__ bptr, const int* __restrict__ ebuf,
                                             int* __restrict__ rowp, int* __restrict__ csr,
                                             float* __restrict__ dinv){
    __shared__ int cnt[256];
    __shared__ int sd[256];
    __shared__ int cur[256];
    const int b = blockIdx.x, t = threadIdx.x;
    const int beg = bptr[b], nE = bptr[b+1] - beg;
    cnt[t] = 0;
    __syncthreads();
    for (int i = t; i < nE; i += 256) atomicAdd(&cnt[ebuf[beg+i] & 255], 1);
    __syncthreads();
    int c = cnt[t];
    sd[t] = c;
    __syncthreads();
    for (int off = 1; off < 256; off <<= 1){
        int a = (t >= off) ? sd[t-off] : 0;
        __syncthreads();
        sd[t] += a;
        __syncthreads();
    }
    int ex = sd[t] - c;          // exclusive prefix within bucket
    cur[t] = ex;
    int v = b*256 + t;
    if (v < NN){
        rowp[v] = beg + ex;
        dinv[v] = rsqrtf((float)(c + 1));     // +1 self-loop
        if (v == NN-1) rowp[NN] = beg + ex + c;
    }
    __syncthreads();
    for (int i = t; i < nE; i += 256){
        int e = ebuf[beg+i];
        int p = atomicAdd(&cur[e & 255], 1);
        csr[beg + p] = e >> 8;   // src node id
    }
}

// ---------------- GEMM1: h1s = fp16((x @ W1) * dinv[row]), [NN][32] ----------------
// 64-row tiles (grid 1563) for occupancy; 2 rows x 4 cols per thread.
__global__ __launch_bounds__(256) void k_gemm1(const float* __restrict__ x, const float* __restrict__ W1,
                                               const float* __restrict__ dinv, __half* __restrict__ h1s){
    __shared__ float xt[64][36];   // stride 36: 16B-aligned float4, 2-way-free banks
    __shared__ float wt[32][32];
    const int tid = threadIdx.x;
    const int row0 = blockIdx.x * 64;
    const int cg = tid & 7;        // col group: cols cg*4..cg*4+3
    const int rp = tid >> 3;       // row pair: rows 2rp, 2rp+1
    float acc[2][4];
    #pragma unroll
    for (int i = 0; i < 2; ++i){ acc[i][0]=0.f; acc[i][1]=0.f; acc[i][2]=0.f; acc[i][3]=0.f; }

    for (int k0 = 0; k0 < INF; k0 += 32){
        { // W tile 32x32
            int kk = tid >> 3, c4 = (tid & 7) * 4;
            *(float4*)&wt[kk][c4] = *(const float4*)&W1[(k0 + kk)*HID + c4];
        }
        #pragma unroll
        for (int l = 0; l < 2; ++l){ // x tile 64x32 = 512 float4, 2 per thread
            int idx = l*256 + tid;
            int rr = idx >> 3, f4 = idx & 7;
            int grow = row0 + rr;
            float4 v = make_float4(0.f, 0.f, 0.f, 0.f);
            if (grow < NN) v = *(const float4*)&x[(size_t)grow*INF + k0 + f4*4];
            *(float4*)&xt[rr][f4*4] = v;
        }
        __syncthreads();
        #pragma unroll
        for (int k = 0; k < 32; ++k){
            float4 w = *(const float4*)&wt[k][cg*4];
            float x0 = xt[2*rp][k];
            float x1 = xt[2*rp+1][k];
            acc[0][0] = fmaf(x0, w.x, acc[0][0]);
            acc[0][1] = fmaf(x0, w.y, acc[0][1]);
            acc[0][2] = fmaf(x0, w.z, acc[0][2]);
            acc[0][3] = fmaf(x0, w.w, acc[0][3]);
            acc[1][0] = fmaf(x1, w.x, acc[1][0]);
            acc[1][1] = fmaf(x1, w.y, acc[1][1]);
            acc[1][2] = fmaf(x1, w.z, acc[1][2]);
            acc[1][3] = fmaf(x1, w.w, acc[1][3]);
        }
        __syncthreads();
    }
    #pragma unroll
    for (int i = 0; i < 2; ++i){
        int r = row0 + 2*rp + i;
        if (r < NN){
            float d = dinv[r];
            union { __half2 h[2]; float2 f; } u;
            u.h[0] = __floats2half2_rn(acc[i][0]*d, acc[i][1]*d);
            u.h[1] = __floats2half2_rn(acc[i][2]*d, acc[i][3]*d);
            *(float2*)&h1s[(size_t)r*HID + cg*4] = u.f;
        }
    }
}

// ---------------- Fused Aggregation1 + bias + ReLU + GEMM2 + dinv: h2s[NN][8] fp16 ----------------
// 32 lanes per node: 16 feature-pair lanes x 2 edge slots; half2 gathers (4B/lane).
__global__ __launch_bounds__(256) void k_agg1f(const __half* __restrict__ h1s, const int* __restrict__ rowp,
                                               const int* __restrict__ csr, const float* __restrict__ dinv,
                                               const float* __restrict__ b1, const float* __restrict__ W2,
                                               __half* __restrict__ h2s){
    __shared__ float w2s[256];   // W2 padded [32][8]
    __shared__ float bs[32];
    {
        int t = threadIdx.x;
        w2s[t] = ((t & 7) < NC) ? W2[(t >> 3)*NC + (t & 7)] : 0.f;
        if (t < 32) bs[t] = b1[t];
    }
    __syncthreads();
    const int lane = threadIdx.x & 31;
    const int v = blockIdx.x*8 + (threadIdx.x >> 5);
    const int half16 = lane >> 4;    // edge slot 0/1
    const int fp = lane & 15;        // feature pair: feats 2fp, 2fp+1
    const __half2* h1v = (const __half2*)h1s;

    float2 a0 = {0.f,0.f}, a1 = {0.f,0.f}, a2 = {0.f,0.f}, a3 = {0.f,0.f};
    const int beg = rowp[v], end = rowp[v+1];
    int e = beg;
    for (; e + 8 <= end; e += 8){
        int s0 = csr[e     + half16];
        int s1 = csr[e + 2 + half16];
        int s2 = csr[e + 4 + half16];
        int s3 = csr[e + 6 + half16];
        float2 f0 = __half22float2(h1v[(size_t)s0*16 + fp]);
        float2 f1 = __half22float2(h1v[(size_t)s1*16 + fp]);
        float2 f2 = __half22float2(h1v[(size_t)s2*16 + fp]);
        float2 f3 = __half22float2(h1v[(size_t)s3*16 + fp]);
        a0.x += f0.x; a0.y += f0.y;
        a1.x += f1.x; a1.y += f1.y;
        a2.x += f2.x; a2.y += f2.y;
        a3.x += f3.x; a3.y += f3.y;
    }
    for (; e + 2 <= end; e += 2){
        int s = csr[e + half16];
        float2 f = __half22float2(h1v[(size_t)s*16 + fp]);
        a0.x += f.x; a0.y += f.y;
    }
    if (e < end && half16 == 0){
        float2 f = __half22float2(h1v[(size_t)csr[e]*16 + fp]);
        a0.x += f.x; a0.y += f.y;
    }
    float tx = (a0.x + a1.x) + (a2.x + a3.x);
    float ty = (a0.y + a1.y) + (a2.y + a3.y);
    // combine the two edge slots (lane ^ 16)
    tx += __shfl_xor(tx, 16, 32);
    ty += __shfl_xor(ty, 16, 32);
    // self-loop + norm + bias + relu
    float2 self = __half22float2(h1v[(size_t)v*16 + fp]);
    float d = dinv[v];
    float rx = fmaxf(d*(tx + self.x) + bs[2*fp],     0.f);
    float ry = fmaxf(d*(ty + self.y) + bs[2*fp + 1], 0.f);
    // in-register 32->8 matmul: p[j] = sum_k relu_k * W2[k][j]
    float p[8];
    #pragma unroll
    for (int j = 0; j < 8; ++j)
        p[j] = fmaf(rx, w2s[(2*fp)*8 + j], ry * w2s[(2*fp + 1)*8 + j]);
    #pragma unroll
    for (int off = 8; off > 0; off >>= 1){
        #pragma unroll
        for (int j = 0; j < 8; ++j) p[j] += __shfl_xor(p[j], off, 16);
    }
    if (lane == 0){
        union { __half2 h[4]; float4 f; } u;
        u.h[0] = __floats2half2_rn(p[0]*d, p[1]*d);
        u.h[1] = __floats2half2_rn(p[2]*d, p[3]*d);
        u.h[2] = __floats2half2_rn(p[4]*d, p[5]*d);
        u.h[3] = __floats2half2_rn(p[6]*d, p[7]*d);
        *(float4*)&h2s[(size_t)v*8] = u.f;
    }
}

// ---------------- Aggregation 2: 32 lanes/node (4 edges x 8 feats), bias+softmax ----------------
__global__ __launch_bounds__(256) void k_agg2(const __half* __restrict__ h2s, const int* __restrict__ rowp,
                                              const int* __restrict__ csr, const float* __restrict__ dinv,
                                              const float* __restrict__ b2, float* __restrict__ out){
    const int lane = threadIdx.x & 31;
    const int v = blockIdx.x*8 + (threadIdx.x >> 5);
    if (v >= NN) return;
    const int f = lane & 7, sub = lane >> 3;   // 4 sub-groups handle interleaved edges
    float acc = 0.f;
    const int beg = rowp[v], end = rowp[v+1];
    for (int e = beg + sub; e < end; e += 4){
        int s = csr[e];
        acc += __half2float(h2s[(size_t)s*8 + f]);
    }
    // reduce the 4 sub-group partials (lanes differing in bits 3,4)
    acc += __shfl_xor(acc, 8, 32);
    acc += __shfl_xor(acc, 16, 32);
    acc += __half2float(h2s[(size_t)v*8 + f]);   // self-loop term
    float logit = (f < NC) ? (dinv[v]*acc + b2[f]) : -INFINITY;
    float m = logit;
    #pragma unroll
    for (int off = 1; off < 8; off <<= 1) m = fmaxf(m, __shfl_xor(m, off, 8));
    float ex = __expf(logit - m);
    float s = ex;
    #pragma unroll
    for (int off = 1; off < 8; off <<= 1) s += __shfl_xor(s, off, 8);
    if (sub == 0 && f < NC) out[(size_t)v*NC + f] = ex / s;
}

extern "C" void kernel_launch(void* const* d_in, const int* in_sizes, int n_in,
                              void* d_out, int out_size, void* d_ws, size_t ws_size,
                              hipStream_t stream){
    const float* x  = (const float*)d_in[0];
    const void*  ei = d_in[1];
    const float* W1 = (const float*)d_in[2];
    const float* b1 = (const float*)d_in[3];
    const float* W2 = (const float*)d_in[4];
    const float* b2 = (const float*)d_in[5];
    float* out = (float*)d_out;

    char* ws = (char*)d_ws;
    size_t off = 0;
    auto alloc = [&](size_t bytes)->char*{
        char* p = ws + off; off += (bytes + 255) & ~(size_t)255; return p;
    };
    int*    ebuf  = (int*)   alloc((size_t)NE*4);
    int*    csr   = (int*)   alloc((size_t)NE*4);
    int*    bhist = (int*)   alloc((size_t)(NBUK+1)*4);
    int*    bptr  = (int*)   alloc((size_t)(NBUK+1)*4);
    int*    bcur  = (int*)   alloc((size_t)(NBUK+1)*4);
    int*    rowp  = (int*)   alloc((size_t)(NN+1)*4);
    float*  dinv  = (float*) alloc((size_t)NN*4);
    __half* h1s   = (__half*)alloc((size_t)NN*HID*2);
    __half* h2s   = (__half*)alloc((size_t)NN*8*2);

    const int G1B = (NN + 63)/64;                   // 1563
    const int SB  = (NE + C_T*C_E - 1)/(C_T*C_E);   // 391

    hipMemsetAsync(bhist, 0, (size_t)(NBUK+1)*4, stream);
    k_bhist  <<<1024, 256, 0, stream>>>(ei, bhist);
    k_bscan  <<<1, 512, 0, stream>>>(bhist, bptr, bcur);
    k_scatter<<<SB, C_T, 0, stream>>>(ei, bcur, ebuf);
    k_csr    <<<NBUK, 256, 0, stream>>>(bptr, ebuf, rowp, csr, dinv);
    k_gemm1  <<<G1B, 256, 0, stream>>>(x, W1, dinv, h1s);
    k_agg1f  <<<NN/8, 256, 0, stream>>>(h1s, rowp, csr, dinv, b1, W2, h2s);
    k_agg2   <<<NN/8, 256, 0, stream>>>(h2s, rowp, csr, dinv, b2, out);
}